// Round 10
// baseline (199.333 us; speedup 1.0000x reference)
//
#include <hip/hip_runtime.h>
#include <hip/hip_bf16.h>

#define NL 10
#define NF 256
#define NP 128   // feature pairs per layer
#define BLOCK 512

__device__ __forceinline__ float fexp2(float x) {
#if defined(__has_builtin)
#if __has_builtin(__builtin_amdgcn_exp2f)
  return __builtin_amdgcn_exp2f(x);   // raw v_exp_f32
#else
  return exp2f(x);
#endif
#else
  return exp2f(x);
#endif
}

// Two points per thread. Forward diffeo + analytic 2x2 Jacobian chain for
// both, sharing the wave-uniform LDS param reads (halves LDS traffic/point)
// and doubling in-wave ILP (R4 measured 35% dep-stall cycles at 4 waves/SIMD).
// All math is the R4-validated scalar form: pk-asm abandoned (R6/R8 NaN).
// Per feature pair (gamma = -log2e/(2s^2), B = -2*gamma*c, C = gamma*c^2):
//   arg = (gamma*u + B)*u + C ;  k = exp2(arg)  ; fused, no 0*inf hazard
//   4 accums per point: {ws, wt, c*ws, c*wt}
// Layer end:  s' = -inv_s2*(u*as - acs),  t' = -inv_s2*(u*at - act).
__global__ __launch_bounds__(BLOCK, 2) void dynamics_kernel(
    const float* __restrict__ x, const float* __restrict__ centers,
    const float* __restrict__ Ws, const float* __restrict__ Wt,
    const float* __restrict__ attr, const float* __restrict__ sigma,
    float* __restrict__ out, int half, int npts) {
  // One 48B record per feature pair (layout identical to R4-validated):
  // [B0,B1,C0,C1 | ws0,ws1,wt0,wt1 | cws0,cws1,cwt0,cwt1]
  __shared__ float P[NL * NP * 12];  // 60 KiB

  const int tid = threadIdx.x;
  const float LOG2E = 1.4426950408889634f;
  const float sig = sigma[0];
  const float inv_s2 = 1.0f / (sig * sig);
  const float gamma = -0.5f * inv_s2 * LOG2E;

  for (int f = tid; f < NL * NF; f += BLOCK) {
    const float c = centers[f];
    const float ws = Ws[f];
    const float wt = Wt[f];
    float* p = &P[(f >> 1) * 12];
    const int h = f & 1;
    p[0 + h] = -2.0f * gamma * c;  // B
    p[2 + h] = gamma * c * c;      // C
    p[4 + h] = ws;
    p[6 + h] = wt;
    p[8 + h] = c * ws;
    p[10 + h] = c * wt;
  }
  __syncthreads();

  // ---- attractor trajectory a = f(attr), wave-parallel over features ----
  // (once per wave, shared by both points)
  float au = attr[0], av = attr[1];
  {
    const int lane = tid & 63;
    for (int l = 0; l < NL; ++l) {
      const float nua = gamma * au;
      float s_p = 0.0f, t_p = 0.0f;
#pragma unroll
      for (int j = 0; j < 2; ++j) {
        const int p = l * NP + j * 64 + lane;
        const float4 a4 = *(const float4*)&P[p * 12];
        const float4 w4 = *(const float4*)&P[p * 12 + 4];
        const float k0 = fexp2(fmaf(au, nua + a4.x, a4.z));
        const float k1 = fexp2(fmaf(au, nua + a4.y, a4.w));
        s_p = fmaf(k0, w4.x, fmaf(k1, w4.y, s_p));
        t_p = fmaf(k0, w4.z, fmaf(k1, w4.w, t_p));
      }
      for (int off = 32; off > 0; off >>= 1) {
        s_p += __shfl_xor(s_p, off);
        t_p += __shfl_xor(t_p, off);
      }
      const float E = fexp2(s_p * LOG2E);
      const float nav = fmaf(av, E, t_p);
      av = au;
      au = nav;
    }
  }

  // ---- main loop: two points (A, B) per thread ----
  const int g0 = blockIdx.x * BLOCK + tid;   // point A
  const int g1 = g0 + half;                  // point B
  const int i0 = g0 < npts ? g0 : 0;
  const int i1 = g1 < npts ? g1 : 0;
  const float2 xiA = ((const float2*)x)[i0];
  const float2 xiB = ((const float2*)x)[i1];
  float uA = xiA.x, vA = xiA.y;
  float uB = xiB.x, vB = xiB.y;
  float JuA0 = 1.0f, JuA1 = 0.0f, JvA0 = 0.0f, JvA1 = 1.0f;
  float JuB0 = 1.0f, JuB1 = 0.0f, JvB0 = 0.0f, JvB1 = 1.0f;

  for (int l = 0; l < NL; ++l) {
    const float nuA = gamma * uA;
    const float nuB = gamma * uB;
    float asA0 = 0.f, asA1 = 0.f, atA0 = 0.f, atA1 = 0.f;
    float acsA0 = 0.f, acsA1 = 0.f, actA0 = 0.f, actA1 = 0.f;
    float asB0 = 0.f, asB1 = 0.f, atB0 = 0.f, atB1 = 0.f;
    float acsB0 = 0.f, acsB1 = 0.f, actB0 = 0.f, actB1 = 0.f;
    const float4* __restrict__ q = (const float4*)&P[l * NP * 12];
#pragma unroll 4
    for (int p = 0; p < NP; ++p) {
      const float4 a4 = q[3 * p + 0];
      const float4 w4 = q[3 * p + 1];
      const float4 x4 = q[3 * p + 2];
      // point A
      const float kA0 = fexp2(fmaf(uA, nuA + a4.x, a4.z));
      const float kA1 = fexp2(fmaf(uA, nuA + a4.y, a4.w));
      asA0 = fmaf(kA0, w4.x, asA0);
      asA1 = fmaf(kA1, w4.y, asA1);
      atA0 = fmaf(kA0, w4.z, atA0);
      atA1 = fmaf(kA1, w4.w, atA1);
      acsA0 = fmaf(kA0, x4.x, acsA0);
      acsA1 = fmaf(kA1, x4.y, acsA1);
      actA0 = fmaf(kA0, x4.z, actA0);
      actA1 = fmaf(kA1, x4.w, actA1);
      // point B (same param regs — LDS read shared)
      const float kB0 = fexp2(fmaf(uB, nuB + a4.x, a4.z));
      const float kB1 = fexp2(fmaf(uB, nuB + a4.y, a4.w));
      asB0 = fmaf(kB0, w4.x, asB0);
      asB1 = fmaf(kB1, w4.y, asB1);
      atB0 = fmaf(kB0, w4.z, atB0);
      atB1 = fmaf(kB1, w4.w, atB1);
      acsB0 = fmaf(kB0, x4.x, acsB0);
      acsB1 = fmaf(kB1, x4.y, acsB1);
      actB0 = fmaf(kB0, x4.z, actB0);
      actB1 = fmaf(kB1, x4.w, actB1);
    }
    // layer update, point A
    {
      const float as = asA0 + asA1, at = atA0 + atA1;
      const float acs = acsA0 + acsA1, act = actA0 + actA1;
      const float E = fexp2(as * LOG2E);
      const float spr = -inv_s2 * fmaf(uA, as, -acs);
      const float tpr = -inv_s2 * fmaf(uA, at, -act);
      const float g = fmaf(vA * E, spr, tpr);
      const float nv = fmaf(vA, E, at);
      const float nJv0 = fmaf(E, JvA0, g * JuA0);
      const float nJv1 = fmaf(E, JvA1, g * JuA1);
      const float tu0 = JuA0, tu1 = JuA1, tu = uA;
      JuA0 = nJv0; JuA1 = nJv1; uA = nv;
      JvA0 = tu0;  JvA1 = tu1;  vA = tu;
    }
    // layer update, point B
    {
      const float as = asB0 + asB1, at = atB0 + atB1;
      const float acs = acsB0 + acsB1, act = actB0 + actB1;
      const float E = fexp2(as * LOG2E);
      const float spr = -inv_s2 * fmaf(uB, as, -acs);
      const float tpr = -inv_s2 * fmaf(uB, at, -act);
      const float g = fmaf(vB * E, spr, tpr);
      const float nv = fmaf(vB, E, at);
      const float nJv0 = fmaf(E, JvB0, g * JuB0);
      const float nJv1 = fmaf(E, JvB1, g * JuB1);
      const float tu0 = JuB0, tu1 = JuB1, tu = uB;
      JuB0 = nJv0; JuB1 = nJv1; uB = nv;
      JvB0 = tu0;  JvB1 = tu1;  vB = tu;
    }
  }

  // ---- epilogue: out = -inv(J^T J)(y - a), per point ----
  {
    const float d0 = uA - au, d1 = vA - av;
    const float G00 = fmaf(JuA0, JuA0, JvA0 * JvA0);
    const float G01 = fmaf(JuA0, JuA1, JvA0 * JvA1);
    const float G11 = fmaf(JuA1, JuA1, JvA1 * JvA1);
    const float detJ = JuA0 * JvA1 - JuA1 * JvA0;
    const float inv_det = 1.0f / (detJ * detJ);
    const float o0 = -(G11 * d0 - G01 * d1) * inv_det;
    const float o1 = -(G00 * d1 - G01 * d0) * inv_det;
    if (g0 < npts) ((float2*)out)[g0] = make_float2(o0, o1);
  }
  {
    const float d0 = uB - au, d1 = vB - av;
    const float G00 = fmaf(JuB0, JuB0, JvB0 * JvB0);
    const float G01 = fmaf(JuB0, JuB1, JvB0 * JvB1);
    const float G11 = fmaf(JuB1, JuB1, JvB1 * JvB1);
    const float detJ = JuB0 * JvB1 - JuB1 * JvB0;
    const float inv_det = 1.0f / (detJ * detJ);
    const float o0 = -(G11 * d0 - G01 * d1) * inv_det;
    const float o1 = -(G00 * d1 - G01 * d0) * inv_det;
    if (g1 < npts) ((float2*)out)[g1] = make_float2(o0, o1);
  }
}

extern "C" void kernel_launch(void* const* d_in, const int* in_sizes, int n_in,
                              void* d_out, int out_size, void* d_ws, size_t ws_size,
                              hipStream_t stream) {
  const float* x       = (const float*)d_in[0];
  const float* centers = (const float*)d_in[1];
  const float* Ws      = (const float*)d_in[2];
  const float* Wt      = (const float*)d_in[3];
  const float* attr    = (const float*)d_in[4];
  const float* sigma   = (const float*)d_in[5];
  float* out = (float*)d_out;

  const int npts = in_sizes[0] / 2;
  const int half = (npts + 1) / 2;
  const int blocks = (half + BLOCK - 1) / BLOCK;

  dynamics_kernel<<<blocks, BLOCK, 0, stream>>>(x, centers, Ws, Wt, attr, sigma,
                                                out, half, npts);
}

// Round 13
// 82.968 us; speedup vs baseline: 2.4025x; 2.4025x over previous
//
#include <hip/hip_runtime.h>
#include <hip/hip_bf16.h>

#define NL 10
#define NF 256
#define NNODE 257            // nodes per layer: u in [-16,16], h = 0.125
#define NENT (NL * NNODE)    // 2570 float4 entries = 41120 B
#define BLOCK 512

__device__ __forceinline__ float fexp2(float x) {
#if defined(__has_builtin)
#if __has_builtin(__builtin_amdgcn_exp2f)
  return __builtin_amdgcn_exp2f(x);
#else
  return exp2f(x);
#endif
#else
  return exp2f(x);
#endif
}

// ---------------------------------------------------------------------------
// Build per-layer lookup tables T[l][j] = {s, h*s', t, h*t'} at u_j = -16+j/8.
// s(u) = sum_i ws_i * exp(-(u-c_i)^2/(2 sig^2)), t likewise with wt;
// s'(u) = -inv_s2 * sum_i (u-c_i) k_i ws_i. Derivatives stored pre-scaled by
// h = 0.125 for Hermite evaluation. 2570 entries, one thread each.
// ---------------------------------------------------------------------------
__global__ __launch_bounds__(256) void build_table(
    const float* __restrict__ centers, const float* __restrict__ Ws,
    const float* __restrict__ Wt, const float* __restrict__ sigma,
    float4* __restrict__ T) {
  const int e = blockIdx.x * 256 + threadIdx.x;
  if (e >= NENT) return;
  const int l = e / NNODE;
  const int j = e - l * NNODE;
  const float u = -16.0f + 0.125f * (float)j;

  const float LOG2E = 1.4426950408889634f;
  const float sig = sigma[0];
  const float inv_s2 = 1.0f / (sig * sig);
  const float gl2 = -0.5f * inv_s2 * LOG2E;  // exp(-d^2/(2s^2)) = exp2(gl2*d^2)

  const float* __restrict__ c = centers + l * NF;
  const float* __restrict__ ws = Ws + l * NF;
  const float* __restrict__ wt = Wt + l * NF;
  float s = 0.f, t = 0.f, sp = 0.f, tp = 0.f;
  for (int i = 0; i < NF; ++i) {
    const float d = u - c[i];
    const float k = fexp2(gl2 * d * d);
    const float kd = k * d;
    s = fmaf(k, ws[i], s);
    t = fmaf(k, wt[i], t);
    sp = fmaf(kd, ws[i], sp);
    tp = fmaf(kd, wt[i], tp);
  }
  const float dscale = -inv_s2 * 0.125f;  // real-units deriv * h
  T[e] = make_float4(s, dscale * sp, t, dscale * tp);
}

// ---------------------------------------------------------------------------
// Main: one thread per point. Each layer step is a cubic-Hermite table lookup
// (value + analytic derivative of the interpolant) + the validated 2x2
// Jacobian chain. No per-feature work remains on the per-point path.
// ---------------------------------------------------------------------------
__global__ __launch_bounds__(BLOCK, 4) void dynamics_kernel(
    const float* __restrict__ x, const float4* __restrict__ Tg,
    const float* __restrict__ attr, float* __restrict__ out, int npts) {
  __shared__ float4 T[NENT];  // 41.1 KiB -> 2 blocks/CU
  const int tid = threadIdx.x;
  for (int i = tid; i < NENT; i += BLOCK) T[i] = Tg[i];
  __syncthreads();

  const float LOG2E = 1.4426950408889634f;

  // One layer step via table: updates (u,v) and Jacobian rows.
#define LAYER_STEP(lbase, u, v, Ju0, Ju1, Jv0, Jv1)                        \
  {                                                                        \
    const float pos = fmaf(u, 8.0f, 128.0f); /* (u+16)/h */                \
    const float jf = floorf(pos);                                          \
    int j = (int)jf;                                                       \
    j = j < 0 ? 0 : (j > NNODE - 2 ? NNODE - 2 : j);                       \
    const float tau = pos - (float)j;                                      \
    const bool uok = (pos >= 0.0f) && (pos <= 256.0f);                     \
    const float4 n0 = T[lbase + j];                                        \
    const float4 n1 = T[lbase + j + 1];                                    \
    const float t2 = tau * tau;                                            \
    const float t3 = t2 * tau;                                             \
    const float h00 = 2.f * t3 - 3.f * t2 + 1.f;                           \
    const float h10 = t3 - 2.f * t2 + tau;                                 \
    const float h01 = 3.f * t2 - 2.f * t3;                                 \
    const float h11 = t3 - t2;                                             \
    const float d00 = 6.f * t2 - 6.f * tau;                                \
    const float d10 = 3.f * t2 - 4.f * tau + 1.f;                          \
    const float d01 = 6.f * tau - 6.f * t2;                                \
    const float d11 = 3.f * t2 - 2.f * tau;                                \
    float sv = fmaf(h00, n0.x, fmaf(h10, n0.y, fmaf(h01, n1.x, h11 * n1.y))); \
    float tv = fmaf(h00, n0.z, fmaf(h10, n0.w, fmaf(h01, n1.z, h11 * n1.w))); \
    float sd = fmaf(d00, n0.x, fmaf(d10, n0.y, fmaf(d01, n1.x, d11 * n1.y))); \
    float td = fmaf(d00, n0.z, fmaf(d10, n0.w, fmaf(d01, n1.z, d11 * n1.w))); \
    sv = uok ? sv : 0.0f;  /* outside table: true values < 1e-15 */        \
    tv = uok ? tv : 0.0f;                                                  \
    sd = uok ? sd * 8.0f : 0.0f;  /* 1/h rescale to real units */          \
    td = uok ? td * 8.0f : 0.0f;                                           \
    const float E = fexp2(sv * LOG2E);                                     \
    const float g = fmaf(v * E, sd, td);                                   \
    const float nv = fmaf(v, E, tv);                                       \
    const float nJv0 = fmaf(E, Jv0, g * Ju0);                              \
    const float nJv1 = fmaf(E, Jv1, g * Ju1);                              \
    const float tu0 = Ju0, tu1 = Ju1, tu = u;                              \
    Ju0 = nJv0; Ju1 = nJv1; u = nv;                                        \
    Jv0 = tu0;  Jv1 = tu1;  v = tu;                                        \
  }

  // ---- attractor trajectory a = f(attr) (same table path, per-thread) ----
  float au = attr[0], av = attr[1];
  {
    float A0 = 1.f, A1 = 0.f, B0 = 0.f, B1 = 1.f;  // dummy Jacobian
    for (int l = 0; l < NL; ++l) {
      LAYER_STEP(l * NNODE, au, av, A0, A1, B0, B1);
    }
  }

  // ---- per-point chain ----
  const int gid = blockIdx.x * BLOCK + tid;
  const int lidx = gid < npts ? gid : 0;
  const float2 xi = ((const float2*)x)[lidx];
  float u = xi.x, v = xi.y;
  float Ju0 = 1.0f, Ju1 = 0.0f;
  float Jv0 = 0.0f, Jv1 = 1.0f;
  for (int l = 0; l < NL; ++l) {
    LAYER_STEP(l * NNODE, u, v, Ju0, Ju1, Jv0, Jv1);
  }
#undef LAYER_STEP

  // after even #layers: u = coord0, v = coord1; same for (au, av)
  const float d0 = u - au, d1 = v - av;
  const float G00 = fmaf(Ju0, Ju0, Jv0 * Jv0);
  const float G01 = fmaf(Ju0, Ju1, Jv0 * Jv1);
  const float G11 = fmaf(Ju1, Ju1, Jv1 * Jv1);
  const float detJ = Ju0 * Jv1 - Ju1 * Jv0;
  const float inv_det = 1.0f / (detJ * detJ);  // det(G) = det(J)^2
  const float o0 = -(G11 * d0 - G01 * d1) * inv_det;
  const float o1 = -(G00 * d1 - G01 * d0) * inv_det;
  if (gid < npts) {
    ((float2*)out)[gid] = make_float2(o0, o1);
  }
}

extern "C" void kernel_launch(void* const* d_in, const int* in_sizes, int n_in,
                              void* d_out, int out_size, void* d_ws, size_t ws_size,
                              hipStream_t stream) {
  const float* x       = (const float*)d_in[0];
  const float* centers = (const float*)d_in[1];
  const float* Ws      = (const float*)d_in[2];
  const float* Wt      = (const float*)d_in[3];
  const float* attr    = (const float*)d_in[4];
  const float* sigma   = (const float*)d_in[5];
  float* out = (float*)d_out;
  float4* T = (float4*)d_ws;  // 41120 B table, rebuilt every launch

  const int npts = in_sizes[0] / 2;
  const int blocks = (npts + BLOCK - 1) / BLOCK;

  build_table<<<(NENT + 255) / 256, 256, 0, stream>>>(centers, Ws, Wt, sigma, T);
  dynamics_kernel<<<blocks, BLOCK, 0, stream>>>(x, T, attr, out, npts);
}